// Round 5
// baseline (1228.910 us; speedup 1.0000x reference)
//
#include <hip/hip_runtime.h>
#include <hip/hip_bf16.h>

#define TS 20
#define DNUM 128
#define NWORDS 16384
#define NBLK 256                    // 1 block/CU; bid>>7 = dir

typedef __attribute__((ext_vector_type(8))) short s8v;
typedef __attribute__((ext_vector_type(4))) float f4v;

#define L2E 1.4426950408889634f

__device__ __forceinline__ unsigned short bf16_rne(float f) {
  union { float f; unsigned u; } x; x.f = f;
  unsigned r = x.u + 0x7fffu + ((x.u >> 16) & 1u);
  return (unsigned short)(r >> 16);
}

// tab2[dir][c][u] = (-L2E*xz, -L2E*xr); tabh[dir][c][u] = 2*L2E*xh
__global__ void build_tab(const float* __restrict__ emb,
                          const float* __restrict__ wkF, const float* __restrict__ bF,
                          const float* __restrict__ wkB, const float* __restrict__ bB,
                          float* __restrict__ tab2, float* __restrict__ tabh) {
  int gid = blockIdx.x * 256 + threadIdx.x;
  if (gid >= 2 * 129 * 768) return;
  int dir = gid / (129 * 768);
  int rem = gid - dir * (129 * 768);
  int c = rem / 768, j = rem - (rem / 768) * 768;
  int g = j >> 8, u = j & 255;
  const float* Wk = dir ? wkB : wkF;
  const float* bb = dir ? bB : bF;
  float s = bb[j];                       // b[0] row = input bias
  const float* er = emb + c * DNUM;
  #pragma unroll 4
  for (int d = 0; d < DNUM; ++d) s = fmaf(er[d], Wk[d * 768 + j], s);
  if (g < 2) tab2[(((size_t)dir * 129 + c) * 256 + u) * 2 + g] = -L2E * s;
  else       tabh[((size_t)dir * 129 + c) * 256 + u] = 2.f * L2E * s;
}

// Pack Wr into bf16 MFMA-B-fragment order (verified r1), pre-scaled per gate.
__global__ void pack_wr(const float* __restrict__ wrF, const float* __restrict__ wrB,
                        uint4* __restrict__ wp) {
  int gid = blockIdx.x * 256 + threadIdx.x;
  if (gid >= 2 * 48 * 8 * 64) return;
  int dir = gid / (48 * 8 * 64);
  int rem = gid - dir * (48 * 8 * 64);
  int ct = rem / (8 * 64);
  int kk = (rem / 64) & 7;
  int lane = rem & 63;
  const float* Wr = dir ? wrB : wrF;
  int n = ct * 16 + (lane & 15);
  int k0 = kk * 32 + (lane >> 4) * 8;
  const float sc = (ct >> 4) == 2 ? (2.f * L2E) : (-L2E);
  union { unsigned short v[8]; uint4 q; } u;
  #pragma unroll
  for (int e = 0; e < 8; ++e) u.v[e] = bf16_rne(sc * Wr[(k0 + e) * 768 + n]);
  wp[gid] = u.q;
}

// 256 blocks (1/CU) x 512 threads (8 waves, 2/SIMD, 256-reg budget).
// Wave = 32 units (2 ct-tiles) x 3 gates; z,r weights in 128 VGPRs, h-gate
// weights in 128KB LDS. 32 words/step (2 m-tiles), single-buffer h state:
//   [mi0 reads+MFMA] b1 [mi1 reads+MFMA (rows16-31) || mi0 epi (writes 0-15)]
//   [mi1 epi] b2  -- disjoint rows make the overlap race-free.
__global__ __launch_bounds__(512, 2) void gru_main(
    const int* __restrict__ chars, const float* __restrict__ tab2,
    const float* __restrict__ tabh, const uint4* __restrict__ wrp,
    const float* __restrict__ bf_, const float* __restrict__ bb_,
    float* __restrict__ out) {
  const int bid = blockIdx.x;
  const int dir = bid >> 7;            // 128 blocks per direction
  const int wslot = bid & 127;
  const float2* T2 = (const float2*)tab2 + (size_t)dir * 129 * 256;
  const float*  TH = tabh + (size_t)dir * 129 * 256;
  const uint4* WP = wrp + dir * (48 * 8 * 64);
  const float* brec = (dir ? bb_ : bf_) + 768;   // b[1] = recurrent bias

  const int tid = threadIdx.x;
  const int w = tid >> 6, lane = tid & 63;
  const int lr = lane >> 4, lc = lane & 15;
  const int u0 = w * 32 + lc, u1 = u0 + 16;      // wave's two unit-tiles

  __shared__ uint4 bhl[8192];                    // 128KB h-gate weights
  __shared__ unsigned short hbf[32][264];        // 16.9KB h state (single buf)
  __shared__ int sch[32 * TS];                   // 2.56KB chars

  for (int i = tid; i < 8192; i += 512) bhl[i] = WP[16384 + i];

  // z,r weights resident: 2 ct x 8 kk x 2 gates = 32 uint4 = 128 VGPRs.
  uint4 Wz[2][8], Wrr[2][8];
  #pragma unroll
  for (int ct = 0; ct < 2; ++ct)
    #pragma unroll
    for (int kk = 0; kk < 8; ++kk) {
      Wz[ct][kk]  = WP[(((w * 2 + ct)) * 8 + kk) * 64 + lane];
      Wrr[ct][kk] = WP[((16 + w * 2 + ct) * 8 + kk) * 64 + lane];
    }

  float brz[2], brr[2], brh[2];
  #pragma unroll
  for (int ct = 0; ct < 2; ++ct) {
    const int u = ct ? u1 : u0;
    brz[ct] = -L2E * brec[u];
    brr[ct] = -L2E * brec[256 + u];
    brh[ct] = 2.f * L2E * brec[512 + u];
  }

  #pragma unroll 1
  for (int grp = 0; grp < 4; ++grp) {
    const int word0 = wslot * 128 + grp * 32;

    for (int i = tid; i < 32 * 264 / 2; i += 512) ((unsigned*)&hbf[0][0])[i] = 0;
    for (int i = tid; i < 32 * TS; i += 512) sch[i] = chars[word0 * TS + i];

    float h0[2][4], h1[2][4];
    #pragma unroll
    for (int ct = 0; ct < 2; ++ct)
      #pragma unroll
      for (int r = 0; r < 4; ++r) { h0[ct][r] = 0.f; h1[ct][r] = 0.f; }

    __syncthreads();

    #pragma unroll 1
    for (int t = 0; t < TS; ++t) {
      const int ts = dir ? (TS - 1 - t) : t;

      // ---- mi0 gather (cc + z,r logits; xh deferred to epilogue) ----
      int cc0[4];
      float2 p0[2][4];
      #pragma unroll
      for (int r = 0; r < 4; ++r) cc0[r] = sch[(lr * 4 + r) * TS + ts];
      #pragma unroll
      for (int ct = 0; ct < 2; ++ct)
        #pragma unroll
        for (int r = 0; r < 4; ++r)
          p0[ct][r] = T2[cc0[r] * 256 + (ct ? u1 : u0)];

      // ---- mi0 MFMA (reads hbf rows 0-15) ----
      f4v a0z[2], a0r[2], a0h[2];
      #pragma unroll
      for (int ct = 0; ct < 2; ++ct) {
        a0z[ct] = f4v{brz[ct], brz[ct], brz[ct], brz[ct]};
        a0r[ct] = f4v{brr[ct], brr[ct], brr[ct], brr[ct]};
        a0h[ct] = f4v{brh[ct], brh[ct], brh[ct], brh[ct]};
      }
      #pragma unroll
      for (int kk = 0; kk < 8; ++kk) {
        const uint4 av = *(const uint4*)&hbf[lc][kk * 32 + lr * 8];
        const s8v aa = __builtin_bit_cast(s8v, av);
        #pragma unroll
        for (int ct = 0; ct < 2; ++ct) {
          const uint4 bh = bhl[((w * 2 + ct) * 8 + kk) * 64 + lane];
          a0z[ct] = __builtin_amdgcn_mfma_f32_16x16x32_bf16(aa, __builtin_bit_cast(s8v, Wz[ct][kk]),  a0z[ct], 0, 0, 0);
          a0r[ct] = __builtin_amdgcn_mfma_f32_16x16x32_bf16(aa, __builtin_bit_cast(s8v, Wrr[ct][kk]), a0r[ct], 0, 0, 0);
          a0h[ct] = __builtin_amdgcn_mfma_f32_16x16x32_bf16(aa, __builtin_bit_cast(s8v, bh),          a0h[ct], 0, 0, 0);
        }
      }
      __syncthreads();   // b1: all rows-0..15 reads complete

      // ---- mi1 gather + MFMA (reads rows 16-31) ----
      int cc1[4];
      float2 p1[2][4];
      #pragma unroll
      for (int r = 0; r < 4; ++r) cc1[r] = sch[(16 + lr * 4 + r) * TS + ts];
      #pragma unroll
      for (int ct = 0; ct < 2; ++ct)
        #pragma unroll
        for (int r = 0; r < 4; ++r)
          p1[ct][r] = T2[cc1[r] * 256 + (ct ? u1 : u0)];

      f4v a1z[2], a1r[2], a1h[2];
      #pragma unroll
      for (int ct = 0; ct < 2; ++ct) {
        a1z[ct] = f4v{brz[ct], brz[ct], brz[ct], brz[ct]};
        a1r[ct] = f4v{brr[ct], brr[ct], brr[ct], brr[ct]};
        a1h[ct] = f4v{brh[ct], brh[ct], brh[ct], brh[ct]};
      }
      #pragma unroll
      for (int kk = 0; kk < 8; ++kk) {
        const uint4 av = *(const uint4*)&hbf[16 + lc][kk * 32 + lr * 8];
        const s8v aa = __builtin_bit_cast(s8v, av);
        #pragma unroll
        for (int ct = 0; ct < 2; ++ct) {
          const uint4 bh = bhl[((w * 2 + ct) * 8 + kk) * 64 + lane];
          a1z[ct] = __builtin_amdgcn_mfma_f32_16x16x32_bf16(aa, __builtin_bit_cast(s8v, Wz[ct][kk]),  a1z[ct], 0, 0, 0);
          a1r[ct] = __builtin_amdgcn_mfma_f32_16x16x32_bf16(aa, __builtin_bit_cast(s8v, Wrr[ct][kk]), a1r[ct], 0, 0, 0);
          a1h[ct] = __builtin_amdgcn_mfma_f32_16x16x32_bf16(aa, __builtin_bit_cast(s8v, bh),          a1h[ct], 0, 0, 0);
        }
      }

      // ---- mi0 epilogue (VALU; overlaps mi1 MFMA; writes rows 0-15) ----
      {
        float q0[2][4];
        #pragma unroll
        for (int ct = 0; ct < 2; ++ct)
          #pragma unroll
          for (int r = 0; r < 4; ++r)
            q0[ct][r] = TH[cc0[r] * 256 + (ct ? u1 : u0)];
        #pragma unroll
        for (int ct = 0; ct < 2; ++ct)
          #pragma unroll
          for (int r = 0; r < 4; ++r) {
            const float z  = __builtin_amdgcn_rcpf(1.f + __builtin_amdgcn_exp2f(p0[ct][r].x + a0z[ct][r]));
            const float rr = __builtin_amdgcn_rcpf(1.f + __builtin_amdgcn_exp2f(p0[ct][r].y + a0r[ct][r]));
            const float hc = fmaf(-2.f, __builtin_amdgcn_rcpf(
                1.f + __builtin_amdgcn_exp2f(fmaf(rr, a0h[ct][r], q0[ct][r]))), 1.f);
            const float hp = h0[ct][r];
            float hn = fmaf(1.f - z, hc - hp, hp);
            hn = (cc0[r] != 0) ? hn : hp;
            h0[ct][r] = hn;
            hbf[lr * 4 + r][ct ? u1 : u0] = bf16_rne(hn);
          }
      }

      // ---- mi1 epilogue (writes rows 16-31) ----
      {
        float q1[2][4];
        #pragma unroll
        for (int ct = 0; ct < 2; ++ct)
          #pragma unroll
          for (int r = 0; r < 4; ++r)
            q1[ct][r] = TH[cc1[r] * 256 + (ct ? u1 : u0)];
        #pragma unroll
        for (int ct = 0; ct < 2; ++ct)
          #pragma unroll
          for (int r = 0; r < 4; ++r) {
            const float z  = __builtin_amdgcn_rcpf(1.f + __builtin_amdgcn_exp2f(p1[ct][r].x + a1z[ct][r]));
            const float rr = __builtin_amdgcn_rcpf(1.f + __builtin_amdgcn_exp2f(p1[ct][r].y + a1r[ct][r]));
            const float hc = fmaf(-2.f, __builtin_amdgcn_rcpf(
                1.f + __builtin_amdgcn_exp2f(fmaf(rr, a1h[ct][r], q1[ct][r]))), 1.f);
            const float hp = h1[ct][r];
            float hn = fmaf(1.f - z, hc - hp, hp);
            hn = (cc1[r] != 0) ? hn : hp;
            h1[ct][r] = hn;
            hbf[16 + lr * 4 + r][ct ? u1 : u0] = bf16_rne(hn);
          }
      }
      __syncthreads();   // b2: writes complete before next step's reads
    }

    // store outputs
    #pragma unroll
    for (int ct = 0; ct < 2; ++ct)
      #pragma unroll
      for (int r = 0; r < 4; ++r) {
        out[(size_t)(word0 + lr * 4 + r) * 512 + dir * 256 + (ct ? u1 : u0)] = h0[ct][r];
        out[(size_t)(word0 + 16 + lr * 4 + r) * 512 + dir * 256 + (ct ? u1 : u0)] = h1[ct][r];
      }
    __syncthreads();   // guard hbf/sch reuse vs next group's init
  }
}

extern "C" void kernel_launch(void* const* d_in, const int* in_sizes, int n_in,
                              void* d_out, int out_size, void* d_ws, size_t ws_size,
                              hipStream_t stream) {
  const int* chars = (const int*)d_in[0];
  const float* emb = (const float*)d_in[1];
  const float* wkF = (const float*)d_in[2];
  const float* wrF = (const float*)d_in[3];
  const float* bF  = (const float*)d_in[4];
  const float* wkB = (const float*)d_in[5];
  const float* wrB = (const float*)d_in[6];
  const float* bB  = (const float*)d_in[7];
  float* outp = (float*)d_out;

  float* tab2 = (float*)d_ws;                                   // 2*129*256*8B  = 528384
  float* tabh = (float*)((char*)d_ws + 528384);                 // 2*129*256*4B  = 264192
  uint4* wrp  = (uint4*)((char*)d_ws + 528384 + 264192);        // 2*48*8*64*16B = 786432

  build_tab<<<(2 * 129 * 768 + 255) / 256, 256, 0, stream>>>(emb, wkF, bF, wkB, bB, tab2, tabh);
  pack_wr<<<(2 * 48 * 8 * 64 + 255) / 256, 256, 0, stream>>>(wrF, wrB, wrp);
  gru_main<<<NBLK, 512, 0, stream>>>(chars, tab2, tabh, wrp, bF, bB, outp);
}

// Round 6
// 746.177 us; speedup vs baseline: 1.6469x; 1.6469x over previous
//
#include <hip/hip_runtime.h>
#include <hip/hip_bf16.h>

#define TS 20
#define DNUM 128
#define NWORDS 16384
#define NBLK 256                    // 1 block/CU; bid>>7 = dir

typedef __attribute__((ext_vector_type(8))) short s8v;
typedef __attribute__((ext_vector_type(4))) float f4v;

#define L2E 1.4426950408889634f

__device__ __forceinline__ unsigned short bf16_rne(float f) {
  union { float f; unsigned u; } x; x.f = f;
  unsigned r = x.u + 0x7fffu + ((x.u >> 16) & 1u);
  return (unsigned short)(r >> 16);
}

// tab2[dir][c][u] = (-L2E*(xz + b_rec_z), -L2E*(xr + b_rec_r)); xg incl b_in.
// tabh[dir][c][u] = 2*L2E*xh.   (b_rec_h cannot fold: it sits inside r*(...))
__global__ void build_tab(const float* __restrict__ emb,
                          const float* __restrict__ wkF, const float* __restrict__ bF,
                          const float* __restrict__ wkB, const float* __restrict__ bB,
                          float* __restrict__ tab2, float* __restrict__ tabh) {
  int gid = blockIdx.x * 256 + threadIdx.x;
  if (gid >= 2 * 129 * 768) return;
  int dir = gid / (129 * 768);
  int rem = gid - dir * (129 * 768);
  int c = rem / 768, j = rem - (rem / 768) * 768;
  int g = j >> 8, u = j & 255;
  const float* Wk = dir ? wkB : wkF;
  const float* bb = dir ? bB : bF;
  float s = bb[j];                       // b[0] row = input bias
  const float* er = emb + c * DNUM;
  #pragma unroll 4
  for (int d = 0; d < DNUM; ++d) s = fmaf(er[d], Wk[d * 768 + j], s);
  if (g < 2) tab2[(((size_t)dir * 129 + c) * 256 + u) * 2 + g] = -L2E * (s + bb[768 + j]);
  else       tabh[((size_t)dir * 129 + c) * 256 + u] = 2.f * L2E * s;
}

// Pack Wr into bf16 MFMA-B-fragment order (verified r1), pre-scaled per gate.
__global__ void pack_wr(const float* __restrict__ wrF, const float* __restrict__ wrB,
                        uint4* __restrict__ wp) {
  int gid = blockIdx.x * 256 + threadIdx.x;
  if (gid >= 2 * 48 * 8 * 64) return;
  int dir = gid / (48 * 8 * 64);
  int rem = gid - dir * (48 * 8 * 64);
  int ct = rem / (8 * 64);
  int kk = (rem / 64) & 7;
  int lane = rem & 63;
  const float* Wr = dir ? wrB : wrF;
  int n = ct * 16 + (lane & 15);
  int k0 = kk * 32 + (lane >> 4) * 8;
  const float sc = (ct >> 4) == 2 ? (2.f * L2E) : (-L2E);
  union { unsigned short v[8]; uint4 q; } u;
  #pragma unroll
  for (int e = 0; e < 8; ++e) u.v[e] = bf16_rne(sc * Wr[(k0 + e) * 768 + n]);
  wp[gid] = u.q;
}

// 256 blocks (1/CU) x 512 threads (8 waves, 2/SIMD, 256-reg cap so acc stays
// in VGPRs). Wave = 32 units x 3 gates; z,r weights resident (128 VGPR),
// h-gate weights in 128KB LDS. 32 words/step as two sequential 16-word
// m-tiles with disjoint-row overlap:
//   [m0 MFMA (reads rows0-15)] b1 [m1 MFMA (reads 16-31) + m0 epi (writes 0-15)]
//   b2 [m1 epi (writes 16-31)]
__global__ __launch_bounds__(512, 2) void gru_main(
    const int* __restrict__ chars, const float* __restrict__ tab2,
    const float* __restrict__ tabh, const uint4* __restrict__ wrp,
    const float* __restrict__ bf_, const float* __restrict__ bb_,
    float* __restrict__ out) {
  const int bid = blockIdx.x;
  const int dir = bid >> 7;            // 128 blocks per direction
  const int wslot = bid & 127;
  const float2* T2 = (const float2*)tab2 + (size_t)dir * 129 * 256;
  const float*  TH = tabh + (size_t)dir * 129 * 256;
  const uint4* WP = wrp + dir * (48 * 8 * 64);
  const float* brec = (dir ? bb_ : bf_) + 768;   // b[1] = recurrent bias

  const int tid = threadIdx.x;
  const int w = tid >> 6, lane = tid & 63;
  const int lr = lane >> 4, lc = lane & 15;
  const int u0 = w * 32 + lc, u1 = u0 + 16;      // wave's two unit-tiles

  __shared__ uint4 bhl[8192];                    // 128KB h-gate weights
  __shared__ unsigned short hbf[32][264];        // 16.9KB h state (single buf)
  __shared__ int sch[32 * TS];                   // 2.56KB chars

  for (int i = tid; i < 8192; i += 512) bhl[i] = WP[16384 + i];

  // z,r weights resident: 2 ct x 8 kk x 2 gates = 32 uint4 = 128 VGPRs.
  uint4 Wz[2][8], Wrr[2][8];
  #pragma unroll
  for (int ct = 0; ct < 2; ++ct)
    #pragma unroll
    for (int kk = 0; kk < 8; ++kk) {
      Wz[ct][kk]  = WP[((w * 2 + ct) * 8 + kk) * 64 + lane];
      Wrr[ct][kk] = WP[((16 + w * 2 + ct) * 8 + kk) * 64 + lane];
    }

  float brh[2];
  brh[0] = 2.f * L2E * brec[512 + u0];
  brh[1] = 2.f * L2E * brec[512 + u1];

  #pragma unroll 1
  for (int grp = 0; grp < 4; ++grp) {
    const int word0 = wslot * 128 + grp * 32;

    for (int i = tid; i < 32 * 264 / 2; i += 512) ((unsigned*)&hbf[0][0])[i] = 0;
    for (int i = tid; i < 32 * TS; i += 512) sch[i] = chars[word0 * TS + i];

    float h0[2][4], h1[2][4];
    #pragma unroll
    for (int ct = 0; ct < 2; ++ct)
      #pragma unroll
      for (int r = 0; r < 4; ++r) { h0[ct][r] = 0.f; h1[ct][r] = 0.f; }

    __syncthreads();

    #pragma unroll 1
    for (int t = 0; t < TS; ++t) {
      const int ts = dir ? (TS - 1 - t) : t;

      // ---- m0 gathers (cc + z,r logits; xh deferred to epilogue) ----
      int cc0[4];
      float2 p0[2][4];
      #pragma unroll
      for (int r = 0; r < 4; ++r) cc0[r] = sch[(lr * 4 + r) * TS + ts];
      #pragma unroll
      for (int ct = 0; ct < 2; ++ct)
        #pragma unroll
        for (int r = 0; r < 4; ++r)
          p0[ct][r] = T2[cc0[r] * 256 + (ct ? u1 : u0)];

      // ---- m0 MFMA (reads rows 0-15) ----
      f4v a0z[2], a0r[2], a0h[2];
      #pragma unroll
      for (int ct = 0; ct < 2; ++ct) {
        a0z[ct] = f4v{0.f, 0.f, 0.f, 0.f};
        a0r[ct] = f4v{0.f, 0.f, 0.f, 0.f};
        a0h[ct] = f4v{brh[ct], brh[ct], brh[ct], brh[ct]};
      }
      #pragma unroll
      for (int kk = 0; kk < 8; ++kk) {
        const uint4 av = *(const uint4*)&hbf[lc][kk * 32 + lr * 8];
        const s8v aa = __builtin_bit_cast(s8v, av);
        #pragma unroll
        for (int ct = 0; ct < 2; ++ct) {
          const uint4 bh = bhl[((w * 2 + ct) * 8 + kk) * 64 + lane];
          a0z[ct] = __builtin_amdgcn_mfma_f32_16x16x32_bf16(aa, __builtin_bit_cast(s8v, Wz[ct][kk]),  a0z[ct], 0, 0, 0);
          a0r[ct] = __builtin_amdgcn_mfma_f32_16x16x32_bf16(aa, __builtin_bit_cast(s8v, Wrr[ct][kk]), a0r[ct], 0, 0, 0);
          a0h[ct] = __builtin_amdgcn_mfma_f32_16x16x32_bf16(aa, __builtin_bit_cast(s8v, bh),          a0h[ct], 0, 0, 0);
        }
      }
      __syncthreads();   // b1: all rows 0-15 reads complete

      // ---- m1 gathers + m1 MFMA (reads rows 16-31; no row conflict) ----
      int cc1[4];
      float2 p1[2][4];
      #pragma unroll
      for (int r = 0; r < 4; ++r) cc1[r] = sch[(16 + lr * 4 + r) * TS + ts];
      #pragma unroll
      for (int ct = 0; ct < 2; ++ct)
        #pragma unroll
        for (int r = 0; r < 4; ++r)
          p1[ct][r] = T2[cc1[r] * 256 + (ct ? u1 : u0)];

      f4v a1z[2], a1r[2], a1h[2];
      #pragma unroll
      for (int ct = 0; ct < 2; ++ct) {
        a1z[ct] = f4v{0.f, 0.f, 0.f, 0.f};
        a1r[ct] = f4v{0.f, 0.f, 0.f, 0.f};
        a1h[ct] = f4v{brh[ct], brh[ct], brh[ct], brh[ct]};
      }
      #pragma unroll
      for (int kk = 0; kk < 8; ++kk) {
        const uint4 av = *(const uint4*)&hbf[16 + lc][kk * 32 + lr * 8];
        const s8v aa = __builtin_bit_cast(s8v, av);
        #pragma unroll
        for (int ct = 0; ct < 2; ++ct) {
          const uint4 bh = bhl[((w * 2 + ct) * 8 + kk) * 64 + lane];
          a1z[ct] = __builtin_amdgcn_mfma_f32_16x16x32_bf16(aa, __builtin_bit_cast(s8v, Wz[ct][kk]),  a1z[ct], 0, 0, 0);
          a1r[ct] = __builtin_amdgcn_mfma_f32_16x16x32_bf16(aa, __builtin_bit_cast(s8v, Wrr[ct][kk]), a1r[ct], 0, 0, 0);
          a1h[ct] = __builtin_amdgcn_mfma_f32_16x16x32_bf16(aa, __builtin_bit_cast(s8v, bh),          a1h[ct], 0, 0, 0);
        }
      }

      // ---- m0 epilogue (writes rows 0-15; overlaps m1 MFMA issue) ----
      {
        float q0[2][4];
        #pragma unroll
        for (int ct = 0; ct < 2; ++ct)
          #pragma unroll
          for (int r = 0; r < 4; ++r)
            q0[ct][r] = TH[cc0[r] * 256 + (ct ? u1 : u0)];
        #pragma unroll
        for (int ct = 0; ct < 2; ++ct)
          #pragma unroll
          for (int r = 0; r < 4; ++r) {
            const float z  = __builtin_amdgcn_rcpf(1.f + __builtin_amdgcn_exp2f(p0[ct][r].x + a0z[ct][r]));
            const float rr = __builtin_amdgcn_rcpf(1.f + __builtin_amdgcn_exp2f(p0[ct][r].y + a0r[ct][r]));
            const float hc = fmaf(-2.f, __builtin_amdgcn_rcpf(
                1.f + __builtin_amdgcn_exp2f(fmaf(rr, a0h[ct][r], q0[ct][r]))), 1.f);
            const float hp = h0[ct][r];
            float hn = fmaf(1.f - z, hc - hp, hp);
            hn = (cc0[r] != 0) ? hn : hp;
            h0[ct][r] = hn;
            hbf[lr * 4 + r][ct ? u1 : u0] = bf16_rne(hn);
          }
      }
      __syncthreads();   // b2: writes 0-15 done, reads 16-31 done

      // ---- m1 epilogue (writes rows 16-31) ----
      {
        float q1[2][4];
        #pragma unroll
        for (int ct = 0; ct < 2; ++ct)
          #pragma unroll
          for (int r = 0; r < 4; ++r)
            q1[ct][r] = TH[cc1[r] * 256 + (ct ? u1 : u0)];
        #pragma unroll
        for (int ct = 0; ct < 2; ++ct)
          #pragma unroll
          for (int r = 0; r < 4; ++r) {
            const float z  = __builtin_amdgcn_rcpf(1.f + __builtin_amdgcn_exp2f(p1[ct][r].x + a1z[ct][r]));
            const float rr = __builtin_amdgcn_rcpf(1.f + __builtin_amdgcn_exp2f(p1[ct][r].y + a1r[ct][r]));
            const float hc = fmaf(-2.f, __builtin_amdgcn_rcpf(
                1.f + __builtin_amdgcn_exp2f(fmaf(rr, a1h[ct][r], q1[ct][r]))), 1.f);
            const float hp = h1[ct][r];
            float hn = fmaf(1.f - z, hc - hp, hp);
            hn = (cc1[r] != 0) ? hn : hp;
            h1[ct][r] = hn;
            hbf[16 + lr * 4 + r][ct ? u1 : u0] = bf16_rne(hn);
          }
      }
      // next step's m0 MFMA reads rows 0-15 (disjoint from these writes);
      // its barrier b1 orders these writes before next m1 reads.
    }

    // store outputs
    #pragma unroll
    for (int ct = 0; ct < 2; ++ct)
      #pragma unroll
      for (int r = 0; r < 4; ++r) {
        out[(size_t)(word0 + lr * 4 + r) * 512 + dir * 256 + (ct ? u1 : u0)] = h0[ct][r];
        out[(size_t)(word0 + 16 + lr * 4 + r) * 512 + dir * 256 + (ct ? u1 : u0)] = h1[ct][r];
      }
    __syncthreads();   // guard hbf/sch reuse vs next group's init
  }
}

extern "C" void kernel_launch(void* const* d_in, const int* in_sizes, int n_in,
                              void* d_out, int out_size, void* d_ws, size_t ws_size,
                              hipStream_t stream) {
  const int* chars = (const int*)d_in[0];
  const float* emb = (const float*)d_in[1];
  const float* wkF = (const float*)d_in[2];
  const float* wrF = (const float*)d_in[3];
  const float* bF  = (const float*)d_in[4];
  const float* wkB = (const float*)d_in[5];
  const float* wrB = (const float*)d_in[6];
  const float* bB  = (const float*)d_in[7];
  float* outp = (float*)d_out;

  float* tab2 = (float*)d_ws;                                   // 2*129*256*8B  = 528384
  float* tabh = (float*)((char*)d_ws + 528384);                 // 2*129*256*4B  = 264192
  uint4* wrp  = (uint4*)((char*)d_ws + 528384 + 264192);        // 2*48*8*64*16B = 786432

  build_tab<<<(2 * 129 * 768 + 255) / 256, 256, 0, stream>>>(emb, wkF, bF, wkB, bB, tab2, tabh);
  pack_wr<<<(2 * 48 * 8 * 64 + 255) / 256, 256, 0, stream>>>(wrF, wrB, wrp);
  gru_main<<<NBLK, 512, 0, stream>>>(chars, tab2, tabh, wrp, bF, bB, outp);
}

// Round 7
// 461.240 us; speedup vs baseline: 2.6644x; 1.6178x over previous
//
#include <hip/hip_runtime.h>
#include <hip/hip_bf16.h>

#define TS 20
#define DNUM 128
#define NWORDS 16384
#define NBLK 256                    // 1 block/CU; bid>>7 = dir

typedef __attribute__((ext_vector_type(8))) short s8v;
typedef __attribute__((ext_vector_type(4))) float f4v;

#define L2E 1.4426950408889634f

__device__ __forceinline__ unsigned short bf16_rne(float f) {
  union { float f; unsigned u; } x; x.f = f;
  unsigned r = x.u + 0x7fffu + ((x.u >> 16) & 1u);
  return (unsigned short)(r >> 16);
}

// tab2[dir][c][u] = (-L2E*(xz + b_rec_z), -L2E*(xr + b_rec_r)); xg incl b_in.
// tabh[dir][c][u] = 2*L2E*xh.   (b_rec_h cannot fold: it sits inside r*(...))
__global__ void build_tab(const float* __restrict__ emb,
                          const float* __restrict__ wkF, const float* __restrict__ bF,
                          const float* __restrict__ wkB, const float* __restrict__ bB,
                          float* __restrict__ tab2, float* __restrict__ tabh) {
  int gid = blockIdx.x * 256 + threadIdx.x;
  if (gid >= 2 * 129 * 768) return;
  int dir = gid / (129 * 768);
  int rem = gid - dir * (129 * 768);
  int c = rem / 768, j = rem - (rem / 768) * 768;
  int g = j >> 8, u = j & 255;
  const float* Wk = dir ? wkB : wkF;
  const float* bb = dir ? bB : bF;
  float s = bb[j];                       // b[0] row = input bias
  const float* er = emb + c * DNUM;
  #pragma unroll 4
  for (int d = 0; d < DNUM; ++d) s = fmaf(er[d], Wk[d * 768 + j], s);
  if (g < 2) tab2[(((size_t)dir * 129 + c) * 256 + u) * 2 + g] = -L2E * (s + bb[768 + j]);
  else       tabh[((size_t)dir * 129 + c) * 256 + u] = 2.f * L2E * s;
}

// Pack Wr into bf16 MFMA-B-fragment order (verified r1), pre-scaled per gate.
__global__ void pack_wr(const float* __restrict__ wrF, const float* __restrict__ wrB,
                        uint4* __restrict__ wp) {
  int gid = blockIdx.x * 256 + threadIdx.x;
  if (gid >= 2 * 48 * 8 * 64) return;
  int dir = gid / (48 * 8 * 64);
  int rem = gid - dir * (48 * 8 * 64);
  int ct = rem / (8 * 64);
  int kk = (rem / 64) & 7;
  int lane = rem & 63;
  const float* Wr = dir ? wrB : wrF;
  int n = ct * 16 + (lane & 15);
  int k0 = kk * 32 + (lane >> 4) * 8;
  const float sc = (ct >> 4) == 2 ? (2.f * L2E) : (-L2E);
  union { unsigned short v[8]; uint4 q; } u;
  #pragma unroll
  for (int e = 0; e < 8; ++e) u.v[e] = bf16_rne(sc * Wr[(k0 + e) * 768 + n]);
  wp[gid] = u.q;
}

// 256 blocks (1/CU) x 1024 threads (16 waves, 4/SIMD, <=128 regs/wave — the
// proven no-spill regime). Wave = 16 units x 3 gates; z,r weights in 64
// VGPRs, h-gate weights in 128KB LDS. m=2: 32 words/step, 80 steps total.
// Single-buffer h state, 2 barriers/step:
//   [cc reads; MFMA m0+m1 (reads rows 0-31)] b1 [epilogues m0,m1 (gathers +
//   gates + writes rows 0-31)] b2
__global__ __launch_bounds__(1024, 4) void gru_main(
    const int* __restrict__ chars, const float* __restrict__ tab2,
    const float* __restrict__ tabh, const uint4* __restrict__ wrp,
    const float* __restrict__ bf_, const float* __restrict__ bb_,
    float* __restrict__ out) {
  const int bid = blockIdx.x;
  const int dir = bid >> 7;            // 128 blocks per direction
  const int wslot = bid & 127;
  const float2* T2 = (const float2*)tab2 + (size_t)dir * 129 * 256;
  const float*  TH = tabh + (size_t)dir * 129 * 256;
  const uint4* WP = wrp + dir * (48 * 8 * 64);
  const float* brec = (dir ? bb_ : bf_) + 768;   // b[1] = recurrent bias

  const int tid = threadIdx.x;
  const int w = tid >> 6, lane = tid & 63;
  const int lr = lane >> 4, lc = lane & 15;
  const int u = w * 16 + lc;           // this wave's unit-tile

  __shared__ uint4 bhl[8192];                    // 128KB h-gate weights
  __shared__ unsigned short hbf[32][272];        // 17.4KB h state; 2-way banks max
  __shared__ int sch[32 * TS];                   // 2.56KB chars

  for (int i = tid; i < 8192; i += 1024) bhl[i] = WP[16384 + i];

  // z,r weights resident: 8 kk x 2 gates = 16 uint4 = 64 VGPRs.
  uint4 Wz[8], Wrr[8];
  #pragma unroll
  for (int kk = 0; kk < 8; ++kk) {
    Wz[kk]  = WP[((0 * 16 + w) * 8 + kk) * 64 + lane];
    Wrr[kk] = WP[((16 + w) * 8 + kk) * 64 + lane];
  }

  const float brh = 2.f * L2E * brec[512 + u];

  #pragma unroll 1
  for (int grp = 0; grp < 4; ++grp) {
    const int word0 = wslot * 128 + grp * 32;

    for (int i = tid; i < 32 * 272 / 2; i += 1024) ((unsigned*)&hbf[0][0])[i] = 0;
    for (int i = tid; i < 32 * TS; i += 1024) sch[i] = chars[word0 * TS + i];

    float h0[4], h1[4];
    #pragma unroll
    for (int r = 0; r < 4; ++r) { h0[r] = 0.f; h1[r] = 0.f; }

    __syncthreads();

    #pragma unroll 1
    for (int t = 0; t < TS; ++t) {
      const int ts = dir ? (TS - 1 - t) : t;

      int cc0[4], cc1[4];
      #pragma unroll
      for (int r = 0; r < 4; ++r) {
        cc0[r] = sch[(lr * 4 + r) * TS + ts];        // broadcast reads (free)
        cc1[r] = sch[(16 + lr * 4 + r) * TS + ts];
      }

      f4v a0z = {0.f, 0.f, 0.f, 0.f}, a0r = a0z, a0h = {brh, brh, brh, brh};
      f4v a1z = a0z, a1r = a0z, a1h = a0h;

      #pragma unroll
      for (int kk = 0; kk < 8; ++kk) {
        const uint4 bh = bhl[(w * 8 + kk) * 64 + lane];
        const s8v aa0 = __builtin_bit_cast(s8v, *(const uint4*)&hbf[lc][kk * 32 + lr * 8]);
        const s8v aa1 = __builtin_bit_cast(s8v, *(const uint4*)&hbf[16 + lc][kk * 32 + lr * 8]);
        a0z = __builtin_amdgcn_mfma_f32_16x16x32_bf16(aa0, __builtin_bit_cast(s8v, Wz[kk]),  a0z, 0, 0, 0);
        a0r = __builtin_amdgcn_mfma_f32_16x16x32_bf16(aa0, __builtin_bit_cast(s8v, Wrr[kk]), a0r, 0, 0, 0);
        a0h = __builtin_amdgcn_mfma_f32_16x16x32_bf16(aa0, __builtin_bit_cast(s8v, bh),      a0h, 0, 0, 0);
        a1z = __builtin_amdgcn_mfma_f32_16x16x32_bf16(aa1, __builtin_bit_cast(s8v, Wz[kk]),  a1z, 0, 0, 0);
        a1r = __builtin_amdgcn_mfma_f32_16x16x32_bf16(aa1, __builtin_bit_cast(s8v, Wrr[kk]), a1r, 0, 0, 0);
        a1h = __builtin_amdgcn_mfma_f32_16x16x32_bf16(aa1, __builtin_bit_cast(s8v, bh),      a1h, 0, 0, 0);
      }
      __syncthreads();   // b1: all row reads complete

      // ---- m0 epilogue (writes rows 0-15) ----
      #pragma unroll
      for (int r = 0; r < 4; ++r) {
        const int off = cc0[r] * 256 + u;
        const float2 p = T2[off];
        const float  q = TH[off];
        const float z  = __builtin_amdgcn_rcpf(1.f + __builtin_amdgcn_exp2f(p.x + a0z[r]));
        const float rr = __builtin_amdgcn_rcpf(1.f + __builtin_amdgcn_exp2f(p.y + a0r[r]));
        const float hc = fmaf(-2.f, __builtin_amdgcn_rcpf(
            1.f + __builtin_amdgcn_exp2f(fmaf(rr, a0h[r], q))), 1.f);
        const float hp = h0[r];
        float hn = fmaf(1.f - z, hc - hp, hp);
        hn = (cc0[r] != 0) ? hn : hp;
        h0[r] = hn;
        hbf[lr * 4 + r][u] = __hip_bfloat16_raw(__float2bfloat16(hn)).x;
      }
      // ---- m1 epilogue (writes rows 16-31) ----
      #pragma unroll
      for (int r = 0; r < 4; ++r) {
        const int off = cc1[r] * 256 + u;
        const float2 p = T2[off];
        const float  q = TH[off];
        const float z  = __builtin_amdgcn_rcpf(1.f + __builtin_amdgcn_exp2f(p.x + a1z[r]));
        const float rr = __builtin_amdgcn_rcpf(1.f + __builtin_amdgcn_exp2f(p.y + a1r[r]));
        const float hc = fmaf(-2.f, __builtin_amdgcn_rcpf(
            1.f + __builtin_amdgcn_exp2f(fmaf(rr, a1h[r], q))), 1.f);
        const float hp = h1[r];
        float hn = fmaf(1.f - z, hc - hp, hp);
        hn = (cc1[r] != 0) ? hn : hp;
        h1[r] = hn;
        hbf[16 + lr * 4 + r][u] = __hip_bfloat16_raw(__float2bfloat16(hn)).x;
      }
      __syncthreads();   // b2: writes complete before next step's reads
    }

    // store this group's outputs
    #pragma unroll
    for (int r = 0; r < 4; ++r) {
      out[(size_t)(word0 + lr * 4 + r) * 512 + dir * 256 + u] = h0[r];
      out[(size_t)(word0 + 16 + lr * 4 + r) * 512 + dir * 256 + u] = h1[r];
    }
    __syncthreads();   // guard hbf/sch reuse vs next group's init
  }
}

extern "C" void kernel_launch(void* const* d_in, const int* in_sizes, int n_in,
                              void* d_out, int out_size, void* d_ws, size_t ws_size,
                              hipStream_t stream) {
  const int* chars = (const int*)d_in[0];
  const float* emb = (const float*)d_in[1];
  const float* wkF = (const float*)d_in[2];
  const float* wrF = (const float*)d_in[3];
  const float* bF  = (const float*)d_in[4];
  const float* wkB = (const float*)d_in[5];
  const float* wrB = (const float*)d_in[6];
  const float* bB  = (const float*)d_in[7];
  float* outp = (float*)d_out;

  float* tab2 = (float*)d_ws;                                   // 2*129*256*8B  = 528384
  float* tabh = (float*)((char*)d_ws + 528384);                 // 2*129*256*4B  = 264192
  uint4* wrp  = (uint4*)((char*)d_ws + 528384 + 264192);        // 2*48*8*64*16B = 786432

  build_tab<<<(2 * 129 * 768 + 255) / 256, 256, 0, stream>>>(emb, wkF, bF, wkB, bB, tab2, tabh);
  pack_wr<<<(2 * 48 * 8 * 64 + 255) / 256, 256, 0, stream>>>(wrF, wrB, wrp);
  gru_main<<<NBLK, 1024, 0, stream>>>(chars, tab2, tabh, wrp, bF, bB, outp);
}

// Round 8
// 321.709 us; speedup vs baseline: 3.8199x; 1.4337x over previous
//
#include <hip/hip_runtime.h>
#include <hip/hip_bf16.h>

#define TS 20
#define DNUM 128
#define NWORDS 16384
#define NBLK 256                    // 1 block/CU; bid>>7 = dir

typedef __attribute__((ext_vector_type(8))) short s8v;
typedef __attribute__((ext_vector_type(4))) float f4v;

#define L2E 1.4426950408889634f

__device__ __forceinline__ unsigned short bf16_rne(float f) {
  union { float f; unsigned u; } x; x.f = f;
  unsigned r = x.u + 0x7fffu + ((x.u >> 16) & 1u);
  return (unsigned short)(r >> 16);
}

// tab2[dir][c][u] = (-L2E*(xz + b_rec_z), -L2E*(xr + b_rec_r)); xg incl b_in.
// tabh[dir][c][u] = 2*L2E*xh.   (b_rec_h cannot fold: it sits inside r*(...))
__global__ void build_tab(const float* __restrict__ emb,
                          const float* __restrict__ wkF, const float* __restrict__ bF,
                          const float* __restrict__ wkB, const float* __restrict__ bB,
                          float* __restrict__ tab2, float* __restrict__ tabh) {
  int gid = blockIdx.x * 256 + threadIdx.x;
  if (gid >= 2 * 129 * 768) return;
  int dir = gid / (129 * 768);
  int rem = gid - dir * (129 * 768);
  int c = rem / 768, j = rem - (rem / 768) * 768;
  int g = j >> 8, u = j & 255;
  const float* Wk = dir ? wkB : wkF;
  const float* bb = dir ? bB : bF;
  float s = bb[j];                       // b[0] row = input bias
  const float* er = emb + c * DNUM;
  #pragma unroll 4
  for (int d = 0; d < DNUM; ++d) s = fmaf(er[d], Wk[d * 768 + j], s);
  if (g < 2) tab2[(((size_t)dir * 129 + c) * 256 + u) * 2 + g] = -L2E * (s + bb[768 + j]);
  else       tabh[((size_t)dir * 129 + c) * 256 + u] = 2.f * L2E * s;
}

// Pack Wr into bf16 MFMA-B-fragment order (verified r1), pre-scaled per gate.
__global__ void pack_wr(const float* __restrict__ wrF, const float* __restrict__ wrB,
                        uint4* __restrict__ wp) {
  int gid = blockIdx.x * 256 + threadIdx.x;
  if (gid >= 2 * 48 * 8 * 64) return;
  int dir = gid / (48 * 8 * 64);
  int rem = gid - dir * (48 * 8 * 64);
  int ct = rem / (8 * 64);
  int kk = (rem / 64) & 7;
  int lane = rem & 63;
  const float* Wr = dir ? wrB : wrF;
  int n = ct * 16 + (lane & 15);
  int k0 = kk * 32 + (lane >> 4) * 8;
  const float sc = (ct >> 4) == 2 ? (2.f * L2E) : (-L2E);
  union { unsigned short v[8]; uint4 q; } u;
  #pragma unroll
  for (int e = 0; e < 8; ++e) u.v[e] = bf16_rne(sc * Wr[(k0 + e) * 768 + n]);
  wp[gid] = u.q;
}

// 256 blocks (1/CU) x 512 threads (8 waves, 2/SIMD, 256-arch-reg envelope).
// Wave = 32 units (2 ct-tiles) x 3 gates, 16 words/step (m=1). z,r weights
// resident in 128 VGPRs; h-gate panel (128KB) in LDS. LDS/word drops 16.5 ->
// 12.5 KB vs r4 because only 8 waves re-read each h row.
__global__ __launch_bounds__(512, 2) void gru_main(
    const int* __restrict__ chars, const float* __restrict__ tab2,
    const float* __restrict__ tabh, const uint4* __restrict__ wrp,
    const float* __restrict__ bf_, const float* __restrict__ bb_,
    float* __restrict__ out) {
  const int bid = blockIdx.x;
  const int dir = bid >> 7;            // 128 blocks per direction
  const int wslot = bid & 127;
  const float2* T2 = (const float2*)tab2 + (size_t)dir * 129 * 256;
  const float*  TH = tabh + (size_t)dir * 129 * 256;
  const uint4* WP = wrp + dir * (48 * 8 * 64);
  const float* brec = (dir ? bb_ : bf_) + 768;   // b[1] = recurrent bias

  const int tid = threadIdx.x;
  const int w = tid >> 6, lane = tid & 63;
  const int lr = lane >> 4, lc = lane & 15;
  const int u0 = w * 32 + lc, u1 = u0 + 16;      // wave's two unit-tiles

  __shared__ uint4 bhl[8192];                    // 128KB h-gate weights
  __shared__ unsigned short hbf[16][264];        // 8.25KB; 528B stride -> 2-way
  __shared__ int sch[16 * TS];                   // 1.28KB chars

  for (int i = tid; i < 8192; i += 512) bhl[i] = WP[16384 + i];

  // z,r weights resident: 2 ct x 8 kk x 2 gates = 32 uint4 = 128 VGPRs.
  uint4 Wz[2][8], Wrr[2][8];
  #pragma unroll
  for (int ct = 0; ct < 2; ++ct)
    #pragma unroll
    for (int kk = 0; kk < 8; ++kk) {
      Wz[ct][kk]  = WP[((w * 2 + ct) * 8 + kk) * 64 + lane];
      Wrr[ct][kk] = WP[((16 + w * 2 + ct) * 8 + kk) * 64 + lane];
    }

  float brh[2];
  brh[0] = 2.f * L2E * brec[512 + u0];
  brh[1] = 2.f * L2E * brec[512 + u1];

  #pragma unroll 1
  for (int grp = 0; grp < 8; ++grp) {
    const int word0 = wslot * 128 + grp * 16;

    for (int i = tid; i < 16 * 264 / 2; i += 512) ((unsigned*)&hbf[0][0])[i] = 0;
    for (int i = tid; i < 16 * TS; i += 512) sch[i] = chars[word0 * TS + i];

    float h[2][4];
    #pragma unroll
    for (int ct = 0; ct < 2; ++ct)
      #pragma unroll
      for (int r = 0; r < 4; ++r) h[ct][r] = 0.f;

    __syncthreads();

    #pragma unroll 1
    for (int t = 0; t < TS; ++t) {
      const int ts = dir ? (TS - 1 - t) : t;

      // cc + table prefetch (L2 latency hides under the MFMA phase)
      int cc[4];
      #pragma unroll
      for (int r = 0; r < 4; ++r) cc[r] = sch[(lr * 4 + r) * TS + ts];
      float2 p[2][4];
      float  q[2][4];
      #pragma unroll
      for (int ct = 0; ct < 2; ++ct)
        #pragma unroll
        for (int r = 0; r < 4; ++r) {
          const int off = cc[r] * 256 + (ct ? u1 : u0);
          p[ct][r] = T2[off];
          q[ct][r] = TH[off];
        }

      f4v az[2], ar[2], ah[2];
      #pragma unroll
      for (int ct = 0; ct < 2; ++ct) {
        az[ct] = f4v{0.f, 0.f, 0.f, 0.f};
        ar[ct] = az[ct];
        ah[ct] = f4v{brh[ct], brh[ct], brh[ct], brh[ct]};
      }
      #pragma unroll
      for (int kk = 0; kk < 8; ++kk) {
        const s8v aa = __builtin_bit_cast(s8v, *(const uint4*)&hbf[lc][kk * 32 + lr * 8]);
        #pragma unroll
        for (int ct = 0; ct < 2; ++ct) {
          const uint4 bh = bhl[((w * 2 + ct) * 8 + kk) * 64 + lane];
          az[ct] = __builtin_amdgcn_mfma_f32_16x16x32_bf16(aa, __builtin_bit_cast(s8v, Wz[ct][kk]),  az[ct], 0, 0, 0);
          ar[ct] = __builtin_amdgcn_mfma_f32_16x16x32_bf16(aa, __builtin_bit_cast(s8v, Wrr[ct][kk]), ar[ct], 0, 0, 0);
          ah[ct] = __builtin_amdgcn_mfma_f32_16x16x32_bf16(aa, __builtin_bit_cast(s8v, bh),          ah[ct], 0, 0, 0);
        }
      }
      __syncthreads();   // b1: all h-row reads complete

      #pragma unroll
      for (int ct = 0; ct < 2; ++ct)
        #pragma unroll
        for (int r = 0; r < 4; ++r) {
          const float z  = __builtin_amdgcn_rcpf(1.f + __builtin_amdgcn_exp2f(p[ct][r].x + az[ct][r]));
          const float rr = __builtin_amdgcn_rcpf(1.f + __builtin_amdgcn_exp2f(p[ct][r].y + ar[ct][r]));
          const float hc = fmaf(-2.f, __builtin_amdgcn_rcpf(
              1.f + __builtin_amdgcn_exp2f(fmaf(rr, ah[ct][r], q[ct][r]))), 1.f);
          const float hp = h[ct][r];
          float hn = fmaf(1.f - z, hc - hp, hp);
          hn = (cc[r] != 0) ? hn : hp;
          h[ct][r] = hn;
          hbf[lr * 4 + r][ct ? u1 : u0] = bf16_rne(hn);
        }
      __syncthreads();   // b2: writes complete before next step's reads
    }

    // store this group's outputs
    #pragma unroll
    for (int ct = 0; ct < 2; ++ct)
      #pragma unroll
      for (int r = 0; r < 4; ++r)
        out[(size_t)(word0 + lr * 4 + r) * 512 + dir * 256 + (ct ? u1 : u0)] = h[ct][r];
    __syncthreads();   // guard hbf/sch reuse vs next group's init
  }
}

extern "C" void kernel_launch(void* const* d_in, const int* in_sizes, int n_in,
                              void* d_out, int out_size, void* d_ws, size_t ws_size,
                              hipStream_t stream) {
  const int* chars = (const int*)d_in[0];
  const float* emb = (const float*)d_in[1];
  const float* wkF = (const float*)d_in[2];
  const float* wrF = (const float*)d_in[3];
  const float* bF  = (const float*)d_in[4];
  const float* wkB = (const float*)d_in[5];
  const float* wrB = (const float*)d_in[6];
  const float* bB  = (const float*)d_in[7];
  float* outp = (float*)d_out;

  float* tab2 = (float*)d_ws;                                   // 2*129*256*8B  = 528384
  float* tabh = (float*)((char*)d_ws + 528384);                 // 2*129*256*4B  = 264192
  uint4* wrp  = (uint4*)((char*)d_ws + 528384 + 264192);        // 2*48*8*64*16B = 786432

  build_tab<<<(2 * 129 * 768 + 255) / 256, 256, 0, stream>>>(emb, wkF, bF, wkB, bB, tab2, tabh);
  pack_wr<<<(2 * 48 * 8 * 64 + 255) / 256, 256, 0, stream>>>(wrF, wrB, wrp);
  gru_main<<<NBLK, 512, 0, stream>>>(chars, tab2, tabh, wrp, bF, bB, outp);
}